// Round 5
// baseline (132.643 us; speedup 1.0000x reference)
//
#include <hip/hip_runtime.h>
#include <hip/hip_bf16.h>

typedef __hip_bfloat16 bf16;
typedef __attribute__((ext_vector_type(8))) short bf16x8;
typedef __attribute__((ext_vector_type(4))) float f32x4;
typedef __attribute__((ext_vector_type(4))) unsigned int u32x4;

#define MFMA_BF16(a, b, c) __builtin_amdgcn_mfma_f32_16x16x32_bf16((a), (b), (c), 0, 0, 0)

static constexpr int B_  = 2;
static constexpr int S_  = 2048;
static constexpr int DM_ = 1024;
static constexpr int H_  = 16;
static constexpr int D_  = 64;
static constexpr int M_  = B_ * S_;   // 4096 rows for all GEMMs

__device__ __forceinline__ void load16(const void* g, void* l) {
  __builtin_amdgcn_global_load_lds(
      (const __attribute__((address_space(1))) void*)g,
      (__attribute__((address_space(3))) void*)l, 16, 0, 0);
}

__device__ __forceinline__ unsigned int pack_bf16(float lo, float hi) {
  const unsigned int ul = __builtin_bit_cast(unsigned short, __float2bfloat16(lo));
  const unsigned int uh = __builtin_bit_cast(unsigned short, __float2bfloat16(hi));
  return (uh << 16) | ul;
}

// ---------------- prep kernels ----------------

__global__ void cvt_f32_bf16_kernel(const float* __restrict__ in,
                                    bf16* __restrict__ out, int n4) {
  int i = blockIdx.x * blockDim.x + threadIdx.x;
  if (i >= n4) return;
  float4 v = ((const float4*)in)[i];
  ushort4 u;
  u.x = __builtin_bit_cast(unsigned short, __float2bfloat16(v.x));
  u.y = __builtin_bit_cast(unsigned short, __float2bfloat16(v.y));
  u.z = __builtin_bit_cast(unsigned short, __float2bfloat16(v.z));
  u.w = __builtin_bit_cast(unsigned short, __float2bfloat16(v.w));
  ((ushort4*)out)[i] = u;
}

// out[n][k] = (bf16) in[k][n], 1024x1024 ; blockIdx.z selects which W
__global__ void transpose_cvt_kernel(const float* __restrict__ w0,
                                     const float* __restrict__ w1,
                                     const float* __restrict__ w2,
                                     const float* __restrict__ w3,
                                     bf16* __restrict__ o0, bf16* __restrict__ o1,
                                     bf16* __restrict__ o2, bf16* __restrict__ o3) {
  __shared__ float t[32][33];
  const float* in = blockIdx.z == 0 ? w0 : blockIdx.z == 1 ? w1 : blockIdx.z == 2 ? w2 : w3;
  bf16* out = blockIdx.z == 0 ? o0 : blockIdx.z == 1 ? o1 : blockIdx.z == 2 ? o2 : o3;
  int tx = threadIdx.x & 31;
  int ty = threadIdx.x >> 5;  // 0..7
  int r0 = blockIdx.y * 32;
  int c0 = blockIdx.x * 32;
#pragma unroll
  for (int yy = 0; yy < 32; yy += 8)
    t[ty + yy][tx] = in[(size_t)(r0 + ty + yy) * DM_ + c0 + tx];
  __syncthreads();
#pragma unroll
  for (int yy = 0; yy < 32; yy += 8)
    out[(size_t)(c0 + ty + yy) * DM_ + r0 + tx] = __float2bfloat16(t[tx][ty + yy]);
}

// ---------------- GEMM: C = A(MxK) * Bt(NxK)^T + bias ----------------
// MODE 2: store fp32 to (M, 1024)                 (output projection)
// MODE 3: fused QKV: Bt has 3072 rows (Wq;Wk;Wv). Q,K -> (B,H,S,D) bf16,
//         V -> (B,H,D,S) bf16, at out + proj*4194304 elems.
template <int MODE>
__global__ __launch_bounds__(256) void gemm_bt_kernel(
    const bf16* __restrict__ A, const bf16* __restrict__ Bt,
    const float* __restrict__ bias, const float* __restrict__ bias2,
    const float* __restrict__ bias3, void* __restrict__ out, int K) {
  __shared__ bf16 As[128 * 32];
  __shared__ bf16 Bs[128 * 32];
  const int tid = threadIdx.x;
  const int wid = tid >> 6, lane = tid & 63;
  const int g = lane >> 4, c = lane & 15;
  const int wr = wid >> 1, wc = wid & 1;  // wave = 64x64 subtile
  const int bm = blockIdx.x, bn = blockIdx.y;

  f32x4 acc[4][4] = {};

  const char* Ag = (const char*)(A + (size_t)bm * 128 * K);
  const char* Bg = (const char*)(Bt + (size_t)bn * 128 * K);
  const int f0 = tid * 16, f1 = f0 + 4096;
  const int r0 = f0 >> 6, cb0 = f0 & 63;
  const int r1 = f1 >> 6;
  const size_t rowbytes = (size_t)K * 2;

  for (int kt = 0; kt < K / 32; ++kt) {
    const size_t koff = (size_t)kt * 64;  // 32 bf16 = 64B
    load16(Ag + (size_t)r0 * rowbytes + koff + cb0, (char*)As + f0);
    load16(Ag + (size_t)r1 * rowbytes + koff + cb0, (char*)As + f1);
    load16(Bg + (size_t)r0 * rowbytes + koff + cb0, (char*)Bs + f0);
    load16(Bg + (size_t)r1 * rowbytes + koff + cb0, (char*)Bs + f1);
    __syncthreads();
    bf16x8 af[4], bfr[4];
#pragma unroll
    for (int mi = 0; mi < 4; ++mi)
      af[mi] = *(const bf16x8*)&As[(wr * 64 + mi * 16 + c) * 32 + g * 8];
#pragma unroll
    for (int ni = 0; ni < 4; ++ni)
      bfr[ni] = *(const bf16x8*)&Bs[(wc * 64 + ni * 16 + c) * 32 + g * 8];
#pragma unroll
    for (int mi = 0; mi < 4; ++mi)
#pragma unroll
      for (int ni = 0; ni < 4; ++ni)
        acc[mi][ni] = MFMA_BF16(af[mi], bfr[ni], acc[mi][ni]);
    __syncthreads();
  }

  // epilogue: C row = (lane>>4)*4 + r, col = lane&15  (per 16x16 frag)
#pragma unroll
  for (int ni = 0; ni < 4; ++ni) {
    const int n_g = bn * 128 + wc * 64 + ni * 16 + c;
    float bv;
    if constexpr (MODE == 3) {
      const int proj = n_g >> 10, ncol = n_g & 1023;
      bv = proj == 0 ? bias[ncol] : proj == 1 ? bias2[ncol] : bias3[ncol];
    } else {
      bv = bias[n_g];
    }
#pragma unroll
    for (int mi = 0; mi < 4; ++mi) {
#pragma unroll
      for (int r = 0; r < 4; ++r) {
        const int m_g = bm * 128 + wr * 64 + mi * 16 + g * 4 + r;
        const float val = acc[mi][ni][r] + bv;
        if constexpr (MODE == 2) {
          ((float*)out)[(size_t)m_g * DM_ + n_g] = val;
        } else {
          const int proj = n_g >> 10, ncol = n_g & 1023;
          const int b = m_g >> 11, s = m_g & (S_ - 1);
          const int h = ncol >> 6, d = ncol & (D_ - 1);
          size_t idx = (size_t)proj * 4194304;
          if (proj < 2)
            idx += (((size_t)(b * H_ + h)) * S_ + s) * D_ + d;
          else
            idx += (((size_t)(b * H_ + h)) * D_ + d) * S_ + s;
          ((bf16*)out)[idx] = __float2bfloat16(val);
        }
      }
    }
  }
}

// ---------------- flash attention ----------------
// Q,K: (B,H,S,D) bf16 ; Vt: (B,H,D,S) bf16 ; Aout: (B,S,H*D) bf16
// Block = 4 waves; handles a BALANCED PAIR of t-quads {j, 31-j} of one bh
// sequentially (33 kv-iters per block, uniform). K/V tiles staged once per
// block into 3-buffer XOR-swizzled LDS via global_load_lds, depth-2 counted
// vmcnt pipeline (never drains to 0 mid-loop). Swapped QK^T in-register
// softmax: lane owns q-row q=c; P^T->B-frag via 16 shfl; O^T = mfma(V^T,P^T).
__global__ __launch_bounds__(256, 4) void flash_attn_kernel(
    const bf16* __restrict__ Q, const bf16* __restrict__ Kg,
    const bf16* __restrict__ Vt, bf16* __restrict__ Aout) {
  __shared__ bf16 KVs[3][2][64 * 64];   // [buf][K=0/V=1][tile] = 48 KB
  const int tid = threadIdx.x;
  const int w = tid >> 6, lane = tid & 63;
  const int g = lane >> 4, c = lane & 15;

  // grid: 512 blocks -> (bh, pair pp); 4 bh per XCD
  const int bid = blockIdx.x;
  const int xcd = bid & 7, loc = bid >> 3;      // loc 0..63
  const int bh = xcd * 4 + (loc & 3);
  const int pp = loc >> 2;                      // 0..15
  const int b = bh >> 4, h = bh & (H_ - 1);

  const float ALPHA2 = 0.125f * 1.44269504f;  // 1/sqrt(64) * log2(e)
  const float THR2 = 11.5f;
  const float NEG_INF = -__builtin_inff();

  // ---- staging geometry (seg = 16B; tile row = 128B = 8 segs) ----
  const char* Kbase = (const char*)(Kg + (size_t)bh * S_ * D_);
  const char* Vbase = (const char*)(Vt + (size_t)bh * D_ * S_);
  const int s0 = tid, s1 = tid + 256;
  const int sr0 = s0 >> 3, sq0 = ((s0 & 7) ^ (sr0 & 7)) << 4;  // swizzled src
  const int sr1 = s1 >> 3, sq1 = ((s1 & 7) ^ (sr1 & 7)) << 4;

  auto stageKV = [&](int kv, int bufi) {
    const char* Krow = Kbase + (size_t)kv * 8192;   // 64 rows * 128B
    const char* Vcol = Vbase + (size_t)kv * 128;
    load16(Krow + sr0 * 128 + sq0, (char*)KVs[bufi][0] + s0 * 16);
    load16(Krow + sr1 * 128 + sq1, (char*)KVs[bufi][0] + s1 * 16);
    load16(Vcol + sr0 * 4096 + sq0, (char*)KVs[bufi][1] + s0 * 16);
    load16(Vcol + sr1 * 4096 + sq1, (char*)KVs[bufi][1] + s1 * 16);
  };

  const int rowlim = w * 16 + c;            // local causal limit on diag tile
  const int src0 = ((g & 1) * 2) * 16 + c;  // P^T transpose source lanes
  const int src1 = src0 + 16;
  const bool ghi = (g >= 2);
  const int cs = c & 7;
  // ds_read byte offset inside tile for (kk, n): n*2048 + c*128 + swz-seg
  int roff[2][4];
#pragma unroll
  for (int kk = 0; kk < 2; ++kk)
#pragma unroll
    for (int n = 0; n < 4; ++n)
      roff[kk][n] = n * 2048 + c * 128 + (((kk * 4 + g) ^ cs) << 4);

#pragma unroll 1
  for (int pass = 0; pass < 2; ++pass) {
    const int j = pass == 0 ? pp : 31 - pp;   // quad index; kv tiles 0..j
    const int t16 = j * 4 + w;                // this wave's 16-row q tile

    // Q B-fragment: lane holds Q[q=c][kk*32+g*8 ..]
    const bf16* Qp = Q + ((size_t)bh * S_ + t16 * 16 + c) * D_;
    bf16x8 qf[2];
    qf[0] = *(const bf16x8*)&Qp[g * 8];
    qf[1] = *(const bf16x8*)&Qp[32 + g * 8];

    f32x4 o[4] = {};
    float m = -1000.0f;
    float lsum = 0.0f;

    // prologue: stage tiles 0,1 (depth 2)
    stageKV(0, 0);
    if (j >= 1) stageKV(1, 1);

    int cb = 0;  // compute buffer for kv
#pragma unroll 1
    for (int kv = 0; kv <= j; ++kv) {
      // counted vmcnt: stage(kv) must be done; stage(kv+1) may stay in flight
      if (kv < j) asm volatile("s_waitcnt vmcnt(4)" ::: "memory");
      else        asm volatile("s_waitcnt vmcnt(0)" ::: "memory");
      __builtin_amdgcn_s_barrier();
      // issue stage(kv+2) into buf (cb+2)%3 (its readers finished pre-barrier)
      if (kv + 2 <= j) {
        int sb = cb + 2; if (sb >= 3) sb -= 3;
        stageKV(kv + 2, sb);
      }

      // ---- compute on buffer cb ----
      const char* Kt = (const char*)KVs[cb][0];
      const char* Vtile = (const char*)KVs[cb][1];
      bf16x8 kf[2][4];
#pragma unroll
      for (int kk = 0; kk < 2; ++kk)
#pragma unroll
        for (int n = 0; n < 4; ++n)
          kf[kk][n] = *(const bf16x8*)(Kt + roff[kk][n]);

      f32x4 st[4] = {};
      __builtin_amdgcn_s_setprio(1);
#pragma unroll
      for (int n = 0; n < 4; ++n) {
        st[n] = MFMA_BF16(kf[0][n], qf[0], st[n]);
        st[n] = MFMA_BF16(kf[1][n], qf[1], st[n]);
      }
      __builtin_amdgcn_s_setprio(0);

      bf16x8 vf[2][4];
#pragma unroll
      for (int kk = 0; kk < 2; ++kk)
#pragma unroll
        for (int n = 0; n < 4; ++n)
          vf[kk][n] = *(const bf16x8*)(Vtile + roff[kk][n]);

      float a[4][4];
#pragma unroll
      for (int n = 0; n < 4; ++n)
#pragma unroll
        for (int r = 0; r < 4; ++r)
          a[n][r] = fmaf(st[n][r], ALPHA2, -m);
      if (kv == j) {
#pragma unroll
        for (int n = 0; n < 4; ++n)
#pragma unroll
          for (int r = 0; r < 4; ++r)
            if (n * 16 + g * 4 + r > rowlim) a[n][r] = NEG_INF;
      }

      // per-q-row max: in-lane tree + 2 cross-g shfl steps
      float dm;
      {
        float t0 = fmaxf(fmaxf(a[0][0], a[0][1]), fmaxf(a[0][2], a[0][3]));
        float t1 = fmaxf(fmaxf(a[1][0], a[1][1]), fmaxf(a[1][2], a[1][3]));
        float t2 = fmaxf(fmaxf(a[2][0], a[2][1]), fmaxf(a[2][2], a[2][3]));
        float t3 = fmaxf(fmaxf(a[3][0], a[3][1]), fmaxf(a[3][2], a[3][3]));
        dm = fmaxf(fmaxf(t0, t1), fmaxf(t2, t3));
      }
      dm = fmaxf(dm, __shfl_xor(dm, 16, 64));
      dm = fmaxf(dm, __shfl_xor(dm, 32, 64));

      if (__any(dm > THR2)) {
        const float sh = fmaxf(dm, 0.0f);
        const float sc = __builtin_amdgcn_exp2f(-sh);
        m += sh;
        lsum *= sc;
#pragma unroll
        for (int n = 0; n < 4; ++n)
#pragma unroll
          for (int r = 0; r < 4; ++r) o[n][r] *= sc;
#pragma unroll
        for (int n = 0; n < 4; ++n)
#pragma unroll
          for (int r = 0; r < 4; ++r) a[n][r] -= sh;
      }

      float p[4][4];
#pragma unroll
      for (int n = 0; n < 4; ++n)
#pragma unroll
        for (int r = 0; r < 4; ++r) p[n][r] = __builtin_amdgcn_exp2f(a[n][r]);
      {
        float q0 = (p[0][0] + p[0][1]) + (p[0][2] + p[0][3]);
        float q1 = (p[1][0] + p[1][1]) + (p[1][2] + p[1][3]);
        float q2 = (p[2][0] + p[2][1]) + (p[2][2] + p[2][3]);
        float q3 = (p[3][0] + p[3][1]) + (p[3][2] + p[3][3]);
        lsum += (q0 + q1) + (q2 + q3);
      }

      unsigned int dw[4][2];
#pragma unroll
      for (int n = 0; n < 4; ++n) {
        dw[n][0] = pack_bf16(p[n][0], p[n][1]);
        dw[n][1] = pack_bf16(p[n][2], p[n][3]);
      }

#pragma unroll
      for (int kk = 0; kk < 2; ++kk) {
        unsigned int bb[4];
        {
          unsigned int lo = __shfl(dw[kk * 2][0], src0, 64);
          unsigned int hi = __shfl(dw[kk * 2 + 1][0], src0, 64);
          bb[0] = ghi ? hi : lo;
        }
        {
          unsigned int lo = __shfl(dw[kk * 2][1], src0, 64);
          unsigned int hi = __shfl(dw[kk * 2 + 1][1], src0, 64);
          bb[1] = ghi ? hi : lo;
        }
        {
          unsigned int lo = __shfl(dw[kk * 2][0], src1, 64);
          unsigned int hi = __shfl(dw[kk * 2 + 1][0], src1, 64);
          bb[2] = ghi ? hi : lo;
        }
        {
          unsigned int lo = __shfl(dw[kk * 2][1], src1, 64);
          unsigned int hi = __shfl(dw[kk * 2 + 1][1], src1, 64);
          bb[3] = ghi ? hi : lo;
        }
        u32x4 bbv = {bb[0], bb[1], bb[2], bb[3]};
        bf16x8 pb = __builtin_bit_cast(bf16x8, bbv);
        __builtin_amdgcn_s_setprio(1);
#pragma unroll
        for (int n = 0; n < 4; ++n) o[n] = MFMA_BF16(vf[kk][n], pb, o[n]);
        __builtin_amdgcn_s_setprio(0);
      }

      cb = (cb == 2) ? 0 : cb + 1;
    }

    // epilogue for this pass
    lsum += __shfl_xor(lsum, 16, 64);
    lsum += __shfl_xor(lsum, 32, 64);
    const float inv = 1.0f / lsum;

    bf16* Arow = Aout + ((size_t)b * S_ + t16 * 16 + c) * (H_ * D_) + h * D_;
#pragma unroll
    for (int n = 0; n < 4; ++n) {
      ushort4 u;
      u.x = __builtin_bit_cast(unsigned short, __float2bfloat16(o[n][0] * inv));
      u.y = __builtin_bit_cast(unsigned short, __float2bfloat16(o[n][1] * inv));
      u.z = __builtin_bit_cast(unsigned short, __float2bfloat16(o[n][2] * inv));
      u.w = __builtin_bit_cast(unsigned short, __float2bfloat16(o[n][3] * inv));
      *(ushort4*)&Arow[n * 16 + g * 4] = u;
    }

    __syncthreads();  // full drain before next pass reuses buffers
  }
}

// ---------------- launcher ----------------

extern "C" void kernel_launch(void* const* d_in, const int* in_sizes, int n_in,
                              void* d_out, int out_size, void* d_ws, size_t ws_size,
                              hipStream_t stream) {
  (void)in_sizes; (void)n_in; (void)out_size; (void)ws_size;
  const float* x  = (const float*)d_in[0];
  const float* Wq = (const float*)d_in[1];
  const float* bq = (const float*)d_in[2];
  const float* Wk = (const float*)d_in[3];
  const float* bk = (const float*)d_in[4];
  const float* Wv = (const float*)d_in[5];
  const float* bv = (const float*)d_in[6];
  const float* Wo = (const float*)d_in[7];
  const float* bo = (const float*)d_in[8];
  float* out = (float*)d_out;

  char* ws = (char*)d_ws;
  bf16* xb  = (bf16*)(ws);                    // 8 MB  (4096x1024 bf16)
  bf16* Wqt = (bf16*)(ws + (8u << 20));       // 2 MB each, CONTIGUOUS (QKV fused)
  bf16* Wkt = (bf16*)(ws + (10u << 20));
  bf16* Wvt = (bf16*)(ws + (12u << 20));
  bf16* Wot = (bf16*)(ws + (14u << 20));
  bf16* Qb  = (bf16*)(ws + (16u << 20));      // 8 MB  (B,H,S,D)  -- +0*4194304
  bf16* Kb  = (bf16*)(ws + (24u << 20));      // 8 MB             -- +1*4194304
  bf16* Vtb = (bf16*)(ws + (32u << 20));      // 8 MB  (B,H,D,S)  -- +2*4194304
  bf16* Ab  = xb;  // attention out reuses xb (xb dead after projections)

  cvt_f32_bf16_kernel<<<4096, 256, 0, stream>>>(x, xb, (M_ * DM_) / 4);
  transpose_cvt_kernel<<<dim3(32, 32, 4), 256, 0, stream>>>(
      Wq, Wk, Wv, Wo, Wqt, Wkt, Wvt, Wot);

  // fused QKV projection: Bt = [Wqt;Wkt;Wvt] (3072 rows), out base = Qb
  gemm_bt_kernel<3><<<dim3(32, 24), 256, 0, stream>>>(
      xb, Wqt, bq, bk, bv, (void*)Qb, DM_);

  flash_attn_kernel<<<dim3(512), 256, 0, stream>>>(Qb, Kb, Vtb, Ab);

  gemm_bt_kernel<2><<<dim3(32, 8), 256, 0, stream>>>(
      Ab, Wot, bo, nullptr, nullptr, (void*)out, DM_);
}

// Round 6
// 121.614 us; speedup vs baseline: 1.0907x; 1.0907x over previous
//
#include <hip/hip_runtime.h>
#include <hip/hip_bf16.h>

typedef __hip_bfloat16 bf16;
typedef __attribute__((ext_vector_type(8))) short bf16x8;
typedef __attribute__((ext_vector_type(4))) float f32x4;
typedef __attribute__((ext_vector_type(4))) unsigned int u32x4;

#define MFMA_BF16(a, b, c) __builtin_amdgcn_mfma_f32_16x16x32_bf16((a), (b), (c), 0, 0, 0)

static constexpr int B_  = 2;
static constexpr int S_  = 2048;
static constexpr int DM_ = 1024;
static constexpr int H_  = 16;
static constexpr int D_  = 64;
static constexpr int M_  = B_ * S_;   // 4096 rows for all GEMMs

__device__ __forceinline__ void load16(const void* g, void* l) {
  __builtin_amdgcn_global_load_lds(
      (const __attribute__((address_space(1))) void*)g,
      (__attribute__((address_space(3))) void*)l, 16, 0, 0);
}

__device__ __forceinline__ unsigned int pack_bf16(float lo, float hi) {
  const unsigned int ul = __builtin_bit_cast(unsigned short, __float2bfloat16(lo));
  const unsigned int uh = __builtin_bit_cast(unsigned short, __float2bfloat16(hi));
  return (uh << 16) | ul;
}

// ---------------- prep kernels ----------------

__global__ void cvt_f32_bf16_kernel(const float* __restrict__ in,
                                    bf16* __restrict__ out, int n4) {
  int i = blockIdx.x * blockDim.x + threadIdx.x;
  if (i >= n4) return;
  float4 v = ((const float4*)in)[i];
  ushort4 u;
  u.x = __builtin_bit_cast(unsigned short, __float2bfloat16(v.x));
  u.y = __builtin_bit_cast(unsigned short, __float2bfloat16(v.y));
  u.z = __builtin_bit_cast(unsigned short, __float2bfloat16(v.z));
  u.w = __builtin_bit_cast(unsigned short, __float2bfloat16(v.w));
  ((ushort4*)out)[i] = u;
}

// out[n][k] = (bf16) in[k][n], 1024x1024 ; blockIdx.z selects which W
__global__ void transpose_cvt_kernel(const float* __restrict__ w0,
                                     const float* __restrict__ w1,
                                     const float* __restrict__ w2,
                                     const float* __restrict__ w3,
                                     bf16* __restrict__ o0, bf16* __restrict__ o1,
                                     bf16* __restrict__ o2, bf16* __restrict__ o3) {
  __shared__ float t[32][33];
  const float* in = blockIdx.z == 0 ? w0 : blockIdx.z == 1 ? w1 : blockIdx.z == 2 ? w2 : w3;
  bf16* out = blockIdx.z == 0 ? o0 : blockIdx.z == 1 ? o1 : blockIdx.z == 2 ? o2 : o3;
  int tx = threadIdx.x & 31;
  int ty = threadIdx.x >> 5;  // 0..7
  int r0 = blockIdx.y * 32;
  int c0 = blockIdx.x * 32;
#pragma unroll
  for (int yy = 0; yy < 32; yy += 8)
    t[ty + yy][tx] = in[(size_t)(r0 + ty + yy) * DM_ + c0 + tx];
  __syncthreads();
#pragma unroll
  for (int yy = 0; yy < 32; yy += 8)
    out[(size_t)(c0 + ty + yy) * DM_ + r0 + tx] = __float2bfloat16(t[tx][ty + yy]);
}

// ---------------- GEMM: C = A(MxK) * Bt(NxK)^T + bias ----------------
// Minimum 2-phase pipeline (T3 recipe): double-buffered LDS, stage(kt+1)
// issued at iter top, counted vmcnt(4) + raw barriers, no vmcnt(0) mid-loop.
// MODE 2: store fp32 to (M, 1024)                 (output projection)
// MODE 3: fused QKV: Bt has 3072 rows (Wq;Wk;Wv). Q,K -> (B,H,S,D) bf16,
//         V -> (B,H,D,S) bf16, at out + proj*4194304 elems.
template <int MODE>
__global__ __launch_bounds__(256) void gemm_bt_kernel(
    const bf16* __restrict__ A, const bf16* __restrict__ Bt,
    const float* __restrict__ bias, const float* __restrict__ bias2,
    const float* __restrict__ bias3, void* __restrict__ out, int K) {
  __shared__ bf16 As[2][128 * 32];
  __shared__ bf16 Bs[2][128 * 32];
  const int tid = threadIdx.x;
  const int wid = tid >> 6, lane = tid & 63;
  const int g = lane >> 4, c = lane & 15;
  const int wr = wid >> 1, wc = wid & 1;  // wave = 64x64 subtile
  const int bm = blockIdx.x, bn = blockIdx.y;

  f32x4 acc[4][4] = {};

  const char* Ag = (const char*)(A + (size_t)bm * 128 * K);
  const char* Bg = (const char*)(Bt + (size_t)bn * 128 * K);
  const int f0 = tid * 16, f1 = f0 + 4096;
  const int r0 = f0 >> 6, cb0 = f0 & 63;
  const int r1 = f1 >> 6;
  const size_t rowbytes = (size_t)K * 2;

  auto stage = [&](int kt, int bufi) {
    const size_t koff = (size_t)kt * 64;  // 32 bf16 = 64B
    load16(Ag + (size_t)r0 * rowbytes + koff + cb0, (char*)As[bufi] + f0);
    load16(Ag + (size_t)r1 * rowbytes + koff + cb0, (char*)As[bufi] + f1);
    load16(Bg + (size_t)r0 * rowbytes + koff + cb0, (char*)Bs[bufi] + f0);
    load16(Bg + (size_t)r1 * rowbytes + koff + cb0, (char*)Bs[bufi] + f1);
  };

  const int NT = K / 32;
  stage(0, 0);
  int cur = 0;
#pragma unroll 1
  for (int kt = 0; kt < NT; ++kt) {
    if (kt + 1 < NT) {
      stage(kt + 1, cur ^ 1);
      asm volatile("s_waitcnt vmcnt(4)" ::: "memory");  // own stage(kt) done
    } else {
      asm volatile("s_waitcnt vmcnt(0)" ::: "memory");
    }
    __builtin_amdgcn_s_barrier();   // all waves' stage(kt) landed

    bf16x8 af[4], bfr[4];
#pragma unroll
    for (int mi = 0; mi < 4; ++mi)
      af[mi] = *(const bf16x8*)&As[cur][(wr * 64 + mi * 16 + c) * 32 + g * 8];
#pragma unroll
    for (int ni = 0; ni < 4; ++ni)
      bfr[ni] = *(const bf16x8*)&Bs[cur][(wc * 64 + ni * 16 + c) * 32 + g * 8];
    __builtin_amdgcn_s_setprio(1);
#pragma unroll
    for (int mi = 0; mi < 4; ++mi)
#pragma unroll
      for (int ni = 0; ni < 4; ++ni)
        acc[mi][ni] = MFMA_BF16(af[mi], bfr[ni], acc[mi][ni]);
    __builtin_amdgcn_s_setprio(0);

    if (kt + 1 < NT) __builtin_amdgcn_s_barrier();  // reads of cur done before
    cur ^= 1;                                       // stage(kt+2) overwrites it
  }

  // epilogue: C row = (lane>>4)*4 + r, col = lane&15  (per 16x16 frag)
#pragma unroll
  for (int ni = 0; ni < 4; ++ni) {
    const int n_g = bn * 128 + wc * 64 + ni * 16 + c;
    float bv;
    if constexpr (MODE == 3) {
      const int proj = n_g >> 10, ncol = n_g & 1023;
      bv = proj == 0 ? bias[ncol] : proj == 1 ? bias2[ncol] : bias3[ncol];
    } else {
      bv = bias[n_g];
    }
#pragma unroll
    for (int mi = 0; mi < 4; ++mi) {
#pragma unroll
      for (int r = 0; r < 4; ++r) {
        const int m_g = bm * 128 + wr * 64 + mi * 16 + g * 4 + r;
        const float val = acc[mi][ni][r] + bv;
        if constexpr (MODE == 2) {
          ((float*)out)[(size_t)m_g * DM_ + n_g] = val;
        } else {
          const int proj = n_g >> 10, ncol = n_g & 1023;
          const int b = m_g >> 11, s = m_g & (S_ - 1);
          const int h = ncol >> 6, d = ncol & (D_ - 1);
          size_t idx = (size_t)proj * 4194304;
          if (proj < 2)
            idx += (((size_t)(b * H_ + h)) * S_ + s) * D_ + d;
          else
            idx += (((size_t)(b * H_ + h)) * D_ + d) * S_ + s;
          ((bf16*)out)[idx] = __float2bfloat16(val);
        }
      }
    }
  }
}

// ---------------- flash attention ----------------
// Q,K: (B,H,S,D) bf16 ; Vt: (B,H,D,S) bf16 ; Aout: (B,S,H*D) bf16
// Block = 4 waves = one t-quad {4j..4j+3} of one bh; all waves share kv range
// 0..j. K/V tiles staged once per block into double-buffered XOR-swizzled LDS
// (global_load_lds, 2-phase pipeline). Swapped QK^T in-register softmax:
// lane owns q-row q=c; P^T->B-frag via 16 shfl; O^T = mfma(V^T, P^T).
// Grid: 1024 blocks (4/CU, 16 waves/CU); 4 bh per XCD, longest quad first.
__global__ __launch_bounds__(256, 4) void flash_attn_kernel(
    const bf16* __restrict__ Q, const bf16* __restrict__ Kg,
    const bf16* __restrict__ Vt, bf16* __restrict__ Aout) {
  __shared__ bf16 Ks[2][64 * 64];
  __shared__ bf16 Vs[2][64 * 64];
  const int tid = threadIdx.x;
  const int w = tid >> 6, lane = tid & 63;
  const int g = lane >> 4, c = lane & 15;

  const int bid = blockIdx.x;
  const int xcd = bid & 7, loc = bid >> 3;      // loc 0..127
  const int bh = xcd * 4 + (loc & 3);
  const int j = 31 - (loc >> 2);                // ntiles = j+1
  const int t = j * 4 + w;
  const int b = bh >> 4, h = bh & (H_ - 1);

  const float ALPHA2 = 0.125f * 1.44269504f;  // 1/sqrt(64) * log2(e)
  const float THR2 = 11.5f;
  const float NEG_INF = -__builtin_inff();

  // ---- staging geometry (seg = 16B; tile row = 128B = 8 segs) ----
  const char* Kbase = (const char*)(Kg + (size_t)bh * S_ * D_);
  const char* Vbase = (const char*)(Vt + (size_t)bh * D_ * S_);
  const int s0 = tid, s1 = tid + 256;
  const int sr0 = s0 >> 3, sq0 = ((s0 & 7) ^ (sr0 & 7)) << 4;  // swizzled src
  const int sr1 = s1 >> 3, sq1 = ((s1 & 7) ^ (sr1 & 7)) << 4;

  // ---- Q B-fragment: lane holds Q[q=c][kk*32+g*8 ..] ----
  const bf16* Qp = Q + ((size_t)bh * S_ + t * 16 + c) * D_;
  bf16x8 qf[2];
  qf[0] = *(const bf16x8*)&Qp[g * 8];
  qf[1] = *(const bf16x8*)&Qp[32 + g * 8];

  f32x4 o[4] = {};
  float m = -1000.0f;
  float lsum = 0.0f;

  const int rowlim = w * 16 + c;            // local causal limit on diag tile
  const int src0 = ((g & 1) * 2) * 16 + c;  // P^T transpose source lanes
  const int src1 = src0 + 16;
  const bool ghi = (g >= 2);
  const int cs = c & 7;
  // ds_read byte offset inside tile for (kk, n): n*2048 + c*128 + swz-seg
  int roff[2][4];
#pragma unroll
  for (int kk = 0; kk < 2; ++kk)
#pragma unroll
    for (int n = 0; n < 4; ++n)
      roff[kk][n] = n * 2048 + c * 128 + (((kk * 4 + g) ^ cs) << 4);

  // prologue: stage kv=0 into buf0
  {
    load16(Kbase + sr0 * 128 + sq0, (char*)Ks[0] + s0 * 16);
    load16(Kbase + sr1 * 128 + sq1, (char*)Ks[0] + s1 * 16);
    load16(Vbase + sr0 * 4096 + sq0, (char*)Vs[0] + s0 * 16);
    load16(Vbase + sr1 * 4096 + sq1, (char*)Vs[0] + s1 * 16);
  }
  __syncthreads();

  int cur = 0;
#pragma unroll 1
  for (int kv = 0; kv <= j; ++kv) {
    // issue next-tile staging (overlaps with compute; drained at barrier)
    if (kv < j) {
      const char* Krow = Kbase + (size_t)(kv + 1) * 8192;   // 64 rows * 128B
      const char* Vcol = Vbase + (size_t)(kv + 1) * 128;
      const int nb = cur ^ 1;
      load16(Krow + sr0 * 128 + sq0, (char*)Ks[nb] + s0 * 16);
      load16(Krow + sr1 * 128 + sq1, (char*)Ks[nb] + s1 * 16);
      load16(Vcol + sr0 * 4096 + sq0, (char*)Vs[nb] + s0 * 16);
      load16(Vcol + sr1 * 4096 + sq1, (char*)Vs[nb] + s1 * 16);
    }

    // ---- compute on buffer cur ----
    const char* Kt = (const char*)Ks[cur];
    const char* Vtile = (const char*)Vs[cur];
    bf16x8 kf[2][4];
#pragma unroll
    for (int kk = 0; kk < 2; ++kk)
#pragma unroll
      for (int n = 0; n < 4; ++n)
        kf[kk][n] = *(const bf16x8*)(Kt + roff[kk][n]);

    f32x4 st[4] = {};
    __builtin_amdgcn_s_setprio(1);
#pragma unroll
    for (int n = 0; n < 4; ++n) {
      st[n] = MFMA_BF16(kf[0][n], qf[0], st[n]);
      st[n] = MFMA_BF16(kf[1][n], qf[1], st[n]);
    }
    __builtin_amdgcn_s_setprio(0);

    bf16x8 vf[2][4];
#pragma unroll
    for (int kk = 0; kk < 2; ++kk)
#pragma unroll
      for (int n = 0; n < 4; ++n)
        vf[kk][n] = *(const bf16x8*)(Vtile + roff[kk][n]);

    float a[4][4];
#pragma unroll
    for (int n = 0; n < 4; ++n)
#pragma unroll
      for (int r = 0; r < 4; ++r)
        a[n][r] = fmaf(st[n][r], ALPHA2, -m);
    if (kv == j) {
#pragma unroll
      for (int n = 0; n < 4; ++n)
#pragma unroll
        for (int r = 0; r < 4; ++r)
          if (n * 16 + g * 4 + r > rowlim) a[n][r] = NEG_INF;
    }

    // per-q-row max: in-lane tree + 2 cross-g shfl steps
    float dm;
    {
      float t0 = fmaxf(fmaxf(a[0][0], a[0][1]), fmaxf(a[0][2], a[0][3]));
      float t1 = fmaxf(fmaxf(a[1][0], a[1][1]), fmaxf(a[1][2], a[1][3]));
      float t2 = fmaxf(fmaxf(a[2][0], a[2][1]), fmaxf(a[2][2], a[2][3]));
      float t3 = fmaxf(fmaxf(a[3][0], a[3][1]), fmaxf(a[3][2], a[3][3]));
      dm = fmaxf(fmaxf(t0, t1), fmaxf(t2, t3));
    }
    dm = fmaxf(dm, __shfl_xor(dm, 16, 64));
    dm = fmaxf(dm, __shfl_xor(dm, 32, 64));

    if (__any(dm > THR2)) {
      const float sh = fmaxf(dm, 0.0f);
      const float sc = __builtin_amdgcn_exp2f(-sh);
      m += sh;
      lsum *= sc;
#pragma unroll
      for (int n = 0; n < 4; ++n)
#pragma unroll
        for (int r = 0; r < 4; ++r) o[n][r] *= sc;
#pragma unroll
      for (int n = 0; n < 4; ++n)
#pragma unroll
        for (int r = 0; r < 4; ++r) a[n][r] -= sh;
    }

    float p[4][4];
#pragma unroll
    for (int n = 0; n < 4; ++n)
#pragma unroll
      for (int r = 0; r < 4; ++r) p[n][r] = __builtin_amdgcn_exp2f(a[n][r]);
    {
      float q0 = (p[0][0] + p[0][1]) + (p[0][2] + p[0][3]);
      float q1 = (p[1][0] + p[1][1]) + (p[1][2] + p[1][3]);
      float q2 = (p[2][0] + p[2][1]) + (p[2][2] + p[2][3]);
      float q3 = (p[3][0] + p[3][1]) + (p[3][2] + p[3][3]);
      lsum += (q0 + q1) + (q2 + q3);
    }

    unsigned int dw[4][2];
#pragma unroll
    for (int n = 0; n < 4; ++n) {
      dw[n][0] = pack_bf16(p[n][0], p[n][1]);
      dw[n][1] = pack_bf16(p[n][2], p[n][3]);
    }

#pragma unroll
    for (int kk = 0; kk < 2; ++kk) {
      unsigned int bb[4];
      {
        unsigned int lo = __shfl(dw[kk * 2][0], src0, 64);
        unsigned int hi = __shfl(dw[kk * 2 + 1][0], src0, 64);
        bb[0] = ghi ? hi : lo;
      }
      {
        unsigned int lo = __shfl(dw[kk * 2][1], src0, 64);
        unsigned int hi = __shfl(dw[kk * 2 + 1][1], src0, 64);
        bb[1] = ghi ? hi : lo;
      }
      {
        unsigned int lo = __shfl(dw[kk * 2][0], src1, 64);
        unsigned int hi = __shfl(dw[kk * 2 + 1][0], src1, 64);
        bb[2] = ghi ? hi : lo;
      }
      {
        unsigned int lo = __shfl(dw[kk * 2][1], src1, 64);
        unsigned int hi = __shfl(dw[kk * 2 + 1][1], src1, 64);
        bb[3] = ghi ? hi : lo;
      }
      u32x4 bbv = {bb[0], bb[1], bb[2], bb[3]};
      bf16x8 pb = __builtin_bit_cast(bf16x8, bbv);
      __builtin_amdgcn_s_setprio(1);
#pragma unroll
      for (int n = 0; n < 4; ++n) o[n] = MFMA_BF16(vf[kk][n], pb, o[n]);
      __builtin_amdgcn_s_setprio(0);
    }

    __syncthreads();   // drains staging vmcnt + all waves done reading cur
    cur ^= 1;
  }

  lsum += __shfl_xor(lsum, 16, 64);
  lsum += __shfl_xor(lsum, 32, 64);
  const float inv = 1.0f / lsum;

  bf16* Arow = Aout + ((size_t)b * S_ + t * 16 + c) * (H_ * D_) + h * D_;
#pragma unroll
  for (int n = 0; n < 4; ++n) {
    ushort4 u;
    u.x = __builtin_bit_cast(unsigned short, __float2bfloat16(o[n][0] * inv));
    u.y = __builtin_bit_cast(unsigned short, __float2bfloat16(o[n][1] * inv));
    u.z = __builtin_bit_cast(unsigned short, __float2bfloat16(o[n][2] * inv));
    u.w = __builtin_bit_cast(unsigned short, __float2bfloat16(o[n][3] * inv));
    *(ushort4*)&Arow[n * 16 + g * 4] = u;
  }
}

// ---------------- launcher ----------------

extern "C" void kernel_launch(void* const* d_in, const int* in_sizes, int n_in,
                              void* d_out, int out_size, void* d_ws, size_t ws_size,
                              hipStream_t stream) {
  (void)in_sizes; (void)n_in; (void)out_size; (void)ws_size;
  const float* x  = (const float*)d_in[0];
  const float* Wq = (const float*)d_in[1];
  const float* bq = (const float*)d_in[2];
  const float* Wk = (const float*)d_in[3];
  const float* bk = (const float*)d_in[4];
  const float* Wv = (const float*)d_in[5];
  const float* bv = (const float*)d_in[6];
  const float* Wo = (const float*)d_in[7];
  const float* bo = (const float*)d_in[8];
  float* out = (float*)d_out;

  char* ws = (char*)d_ws;
  bf16* xb  = (bf16*)(ws);                    // 8 MB  (4096x1024 bf16)
  bf16* Wqt = (bf16*)(ws + (8u << 20));       // 2 MB each, CONTIGUOUS (QKV fused)
  bf16* Wkt = (bf16*)(ws + (10u << 20));
  bf16* Wvt = (bf16*)(ws + (12u << 20));
  bf16* Wot = (bf16*)(ws + (14u << 20));
  bf16* Qb  = (bf16*)(ws + (16u << 20));      // 8 MB  (B,H,S,D)  -- +0*4194304
  bf16* Kb  = (bf16*)(ws + (24u << 20));      // 8 MB             -- +1*4194304
  bf16* Vtb = (bf16*)(ws + (32u << 20));      // 8 MB  (B,H,D,S)  -- +2*4194304
  bf16* Ab  = xb;  // attention out reuses xb (xb dead after projections)

  cvt_f32_bf16_kernel<<<4096, 256, 0, stream>>>(x, xb, (M_ * DM_) / 4);
  transpose_cvt_kernel<<<dim3(32, 32, 4), 256, 0, stream>>>(
      Wq, Wk, Wv, Wo, Wqt, Wkt, Wvt, Wot);

  // fused QKV projection: Bt = [Wqt;Wkt;Wvt] (3072 rows), out base = Qb
  gemm_bt_kernel<3><<<dim3(32, 24), 256, 0, stream>>>(
      xb, Wqt, bq, bk, bv, (void*)Qb, DM_);

  flash_attn_kernel<<<dim3(1024), 256, 0, stream>>>(Qb, Kb, Vtb, Ab);

  gemm_bt_kernel<2><<<dim3(32, 8), 256, 0, stream>>>(
      Ab, Wot, bo, nullptr, nullptr, (void*)out, DM_);
}